// Round 6
// baseline (1759.456 us; speedup 1.0000x reference)
//
#include <hip/hip_runtime.h>

typedef unsigned short u16;
typedef unsigned int u32;
typedef __attribute__((ext_vector_type(8))) short short8;   // 8 x bf16 raw
typedef __attribute__((ext_vector_type(4))) float floatx4;  // MFMA acc
typedef __attribute__((ext_vector_type(4))) float f32x4v;   // nt-store vector

constexpr int Bc = 2, Sc = 2048, Ec = 2048, Hc = 16, Dc = 128;
constexpr int TILE = 128, BK = 64;

// fp32 -> bf16 raw bits, round-to-nearest-even
__device__ __forceinline__ u16 f2bf(float f) {
  u32 u = __builtin_bit_cast(u32, f);
  u = (u + 0x7FFFu + ((u >> 16) & 1u)) >> 16;
  return (u16)u;
}

__device__ __forceinline__ float bf2f(short s) {
  u32 u = ((u32)(u16)s) << 16;
  return __builtin_bit_cast(float, u);
}

__device__ __forceinline__ short8 pack2(float4 a, float4 b) {
  short8 r;
  r[0] = (short)f2bf(a.x); r[1] = (short)f2bf(a.y);
  r[2] = (short)f2bf(a.z); r[3] = (short)f2bf(a.w);
  r[4] = (short)f2bf(b.x); r[5] = (short)f2bf(b.y);
  r[6] = (short)f2bf(b.z); r[7] = (short)f2bf(b.w);
  return r;
}

// async 16B global -> LDS (DMA). LDS dest is wave-uniform base + lane*16.
__device__ __forceinline__ void glds16(const u16* g, u16* l) {
  __builtin_amdgcn_global_load_lds(
      (const __attribute__((address_space(1))) u32*)g,
      (__attribute__((address_space(3))) u32*)l, 16, 0, 0);
}

// 128x128 tile GEMM core, BK=64 (2 MFMA k-slices per barrier pair).
// C[m][n] = sum_k A[m][k] * Bt[n][k], both bf16 K-major.
// 256 threads = 4 waves 2x2; each wave 4x4 MFMA tiles of 16x16x32 bf16.
// LDS [128][64] bf16 per operand; chunk c of row r at physical slot c^(r&7),
// staged via pre-swizzled global source (see round-5 notes).
__device__ __forceinline__ void gemm_core(const u16* __restrict__ A, int lda,
                                          const u16* __restrict__ Bt, int ldb,
                                          int K, int m0, int n0,
                                          u16* smA, u16* smB,
                                          floatx4 (*acc)[4]) {
  const int t = threadIdx.x;
  const int lane = t & 63;
  const int w = t >> 6;
  const int wr = (w >> 1) * 64, wc = (w & 1) * 64;
  const int l15 = lane & 15, q = lane >> 4;

  const int r0 = t >> 3;                 // 0..31
  const int c0 = (t & 7) ^ (r0 & 7);     // pre-swizzled logical k-chunk
  const u16* Ap = A + (size_t)(m0 + r0) * lda + c0 * 8;
  const u16* Bp = Bt + (size_t)(n0 + r0) * ldb + c0 * 8;
  u16* dA = smA + w * 512;               // + j*2048 per 32-row group
  u16* dB = smB + w * 512;

  for (int k0 = 0; k0 < K; k0 += BK) {
    #pragma unroll
    for (int j = 0; j < 4; j++) {
      glds16(Ap + (size_t)(32 * j) * lda + k0, dA + j * 2048);
      glds16(Bp + (size_t)(32 * j) * ldb + k0, dB + j * 2048);
    }
    __syncthreads();                     // drains vmcnt before ds_read

    #pragma unroll
    for (int ks = 0; ks < 2; ks++) {
      short8 af[4], bfr[4];
      #pragma unroll
      for (int i = 0; i < 4; i++) {
        int ra = wr + i * 16 + l15;
        af[i] = *(const short8*)&smA[ra * BK + (((ks * 4 + q) ^ (ra & 7)) << 3)];
        int rb = wc + i * 16 + l15;
        bfr[i] = *(const short8*)&smB[rb * BK + (((ks * 4 + q) ^ (rb & 7)) << 3)];
      }
      #pragma unroll
      for (int mi = 0; mi < 4; mi++)
        #pragma unroll
        for (int ni = 0; ni < 4; ni++)
          acc[mi][ni] = __builtin_amdgcn_mfma_f32_16x16x32_bf16(af[mi], bfr[ni], acc[mi][ni], 0, 0, 0);
    }
    __syncthreads();
  }
}

// ---- weight pre-transpose: WT[n][k] (bf16) from W[k][n] (fp32) ----
__global__ __launch_bounds__(256) void transpose_w(
    const float* __restrict__ Wq, const float* __restrict__ Wk,
    const float* __restrict__ Wv, const float* __restrict__ Wo,
    u16* __restrict__ WT, u16* __restrict__ WoT) {
  __shared__ float tile[32][33];
  const int z = blockIdx.z;
  const float* W = (z == 0) ? Wq : (z == 1) ? Wk : (z == 2) ? Wv : Wo;
  u16* dst = (z < 3) ? (WT + (size_t)z * Ec * Ec) : WoT;
  const int n0 = blockIdx.x * 32, k0 = blockIdx.y * 32;
  const int tx = threadIdx.x, ty = threadIdx.y;
  #pragma unroll
  for (int i = 0; i < 4; i++)
    tile[ty + 8 * i][tx] = W[(size_t)(k0 + ty + 8 * i) * Ec + n0 + tx];
  __syncthreads();
  #pragma unroll
  for (int i = 0; i < 4; i++)
    dst[(size_t)(n0 + ty + 8 * i) * Ec + k0 + tx] = f2bf(tile[tx][ty + 8 * i]);
}

// ---- x -> bf16; zero s1; bit-pack mask (absorbed, no extra dispatch) ----
__global__ __launch_bounds__(256) void xcvt_kernel(const float* __restrict__ x,
                                                   u16* __restrict__ xb,
                                                   float* __restrict__ s1,
                                                   const int* __restrict__ mp,
                                                   u32* __restrict__ mb) {
  const int i = blockIdx.x * 256 + threadIdx.x;
  const float4 f0 = ((const float4*)x)[(size_t)i * 2];
  const float4 f1 = ((const float4*)x)[(size_t)i * 2 + 1];
  *(short8*)&xb[(size_t)i * 8] = pack2(f0, f1);
  if (blockIdx.x < 64)
    ((float4*)s1)[i] = make_float4(0.f, 0.f, 0.f, 0.f);  // 64*256*4 = 65536 floats
  if (blockIdx.x < 1024) {                                // 1024*256 = 262144 words
    const int4* src = (const int4*)mp + (size_t)i * 8;
    u32 wv = 0;
    #pragma unroll
    for (int j = 0; j < 8; j++) {
      const int4 v = src[j];
      wv |= (u32)(v.x != 0) << (j * 4 + 0);
      wv |= (u32)(v.y != 0) << (j * 4 + 1);
      wv |= (u32)(v.z != 0) << (j * 4 + 2);
      wv |= (u32)(v.w != 0) << (j * 4 + 3);
    }
    mb[i] = wv;
  }
}

// ---- K1: fused QKV GEMM (N=6144 concat, bf16 A) + bias + RoPE ----
__global__ __launch_bounds__(256) void qkv_kernel(
    const u16* __restrict__ xb, const u16* __restrict__ WT,
    const float* __restrict__ bq, const float* __restrict__ bk, const float* __restrict__ bv,
    const float* __restrict__ sinp, const float* __restrict__ cosp,
    u16* __restrict__ qr, u16* __restrict__ kr, u16* __restrict__ vT) {
  __shared__ __align__(16) u16 smA[TILE * BK];
  __shared__ __align__(16) u16 smB[TILE * BK];
  floatx4 acc[4][4] = {};
  // XCD-aware swizzle: 1536 blocks = 8 * 192
  const int lin = blockIdx.y * 48 + blockIdx.x;
  const int swz = (lin & 7) * 192 + (lin >> 3);
  const int m0 = (swz / 48) * TILE, n0 = (swz % 48) * TILE;
  gemm_core(xb, Ec, WT, Ec, Ec, m0, n0, smA, smB, acc);

  const int t = threadIdx.x, lane = t & 63, w = t >> 6;
  const int wr = (w >> 1) * 64, wc = (w & 1) * 64, l15 = lane & 15, q = lane >> 4;
  #pragma unroll
  for (int mi = 0; mi < 4; mi++) {
    #pragma unroll
    for (int ni = 0; ni < 4; ni++) {
      const int gcol = n0 + wc + ni * 16 + l15;
      const int which = gcol >> 11;          // 0:q 1:k 2:v
      const int e = gcol & 2047, h = e >> 7, d = e & 127;
      const float* bp = (which == 0) ? bq : (which == 1) ? bk : bv;
      const float bias = bp[e];
      #pragma unroll
      for (int rr = 0; rr < 4; rr++) {
        const int grow = m0 + wr + mi * 16 + q * 4 + rr;
        const int b = grow >> 11, s = grow & 2047;
        float val = acc[mi][ni][rr] + bias;
        float pv = __shfl_xor(val, 1);       // partner column (d^1), same row
        if (which < 2) {
          const size_t sc = ((size_t)h * Sc + s) * Dc + d;
          const float c = cosp[sc], sn = sinp[sc];
          const float o = val * c + ((d & 1) ? pv : -pv) * sn;
          u16* dst = which ? kr : qr;
          __builtin_nontemporal_store((u16)f2bf(o),
              &dst[(((size_t)b * Hc + h) * Sc + s) * Dc + d]);
        } else {
          __builtin_nontemporal_store((u16)f2bf(val),
              &vT[(((size_t)b * Hc + h) * Dc + d) * Sc + s]);
        }
      }
    }
  }
}

// ---- K2: P = exp(mask(q k^T / sqrt(D))) -> bf16 Pbuf (nt); s1 += per-row sum P ----
__global__ __launch_bounds__(256) void logits_kernel(
    const u16* __restrict__ qr, const u16* __restrict__ kr,
    const u32* __restrict__ mb, u16* __restrict__ Pbuf, float* __restrict__ s1) {
  __shared__ __align__(16) u16 smA[TILE * BK];
  __shared__ __align__(16) u16 smB[TILE * BK];
  floatx4 acc[4][4] = {};
  const int z = blockIdx.z;                  // b*H + h
  const int m0 = blockIdx.y * TILE, n0 = blockIdx.x * TILE;
  gemm_core(qr + (size_t)z * Sc * Dc, Dc, kr + (size_t)z * Sc * Dc, Dc, Dc, m0, n0, smA, smB, acc);

  u16* Pp = Pbuf + (size_t)z * Sc * Sc;
  const int b = z >> 4;
  const float scale = 0.08838834764831845f;  // 1/sqrt(128)
  const int t = threadIdx.x, lane = t & 63, w = t >> 6;
  const int wr = (w >> 1) * 64, wc = (w & 1) * 64, l15 = lane & 15, q = lane >> 4;
  const int wbase = (n0 + wc) >> 5;          // (n0+wc) % 32 == 0

  #pragma unroll
  for (int mi = 0; mi < 4; mi++)
    #pragma unroll
    for (int rr = 0; rr < 4; rr++) {
      const int grow = m0 + wr + mi * 16 + q * 4 + rr;
      const u32* mrow = mb + ((size_t)b * Sc + grow) * (Sc / 32) + wbase;
      const u32 w0 = mrow[0], w1 = mrow[1];  // the wave's 64-col span
      float rsv = 0.f;
      #pragma unroll
      for (int ni = 0; ni < 4; ni++) {
        const int gcol = n0 + wc + ni * 16 + l15;
        const u32 mw = (ni < 2) ? w0 : w1;
        const int mv = (mw >> (gcol & 31)) & 1;
        const float val = mv ? acc[mi][ni][rr] * scale : -9.0e15f;
        const float pe = __expf(val);        // exp(-9e15) -> 0
        rsv += pe;
        __builtin_nontemporal_store((u16)f2bf(pe), &Pp[(size_t)grow * Sc + gcol]);
      }
      rsv += __shfl_xor(rsv, 1);
      rsv += __shfl_xor(rsv, 2);
      rsv += __shfl_xor(rsv, 4);
      rsv += __shfl_xor(rsv, 8);
      if (l15 == 0) atomicAdd(&s1[z * Sc + grow], rsv);
    }
}

// ---- K3: valT = ((P @ v) * inv1)^T ; s2[row] = sum_k exp(P[row][k]*inv1) ----
// M-tile 64, BK=64; epilogue transposes via LDS for coalesced valT writes.
__global__ __launch_bounds__(256) void av_kernel(
    const u16* __restrict__ P, const u16* __restrict__ vT,
    const float* __restrict__ s1, u16* __restrict__ valT, float* __restrict__ s2) {
  __shared__ __align__(16) u16 smA[64 * BK];    // [64][64] 8KB
  __shared__ __align__(16) u16 smB[128 * BK];   // [128][64] 16KB
  floatx4 acc[4][2] = {};
  const int z = blockIdx.z;
  const int m0 = blockIdx.y * 64;
  const int t = threadIdx.x, lane = t & 63, w = t >> 6;
  const int wc = w * 32;
  const int l15 = lane & 15, q = lane >> 4;

  const int r0 = t >> 3;               // 0..31
  const int c0 = (t & 7) ^ (r0 & 7);   // pre-swizzled logical k-chunk
  const u16* Pb = P + (size_t)z * Sc * Sc;
  const u16* Ap = Pb + (size_t)(m0 + r0) * Sc + c0 * 8;   // A rows r0, r0+32
  const u16* Bp = vT + (size_t)z * Dc * Sc + (size_t)r0 * Sc + c0 * 8;
  u16* dA = smA + w * 512;
  u16* dB = smB + w * 512;

  const float inv1a = 1.0f / s1[z * Sc + m0 + r0];
  const float inv1b = 1.0f / s1[z * Sc + m0 + r0 + 32];
  float s2a = 0.0f, s2b = 0.0f;

  for (int k0 = 0; k0 < Sc; k0 += BK) {
    glds16(Ap + k0, dA);
    glds16(Ap + (size_t)32 * Sc + k0, dA + 2048);
    #pragma unroll
    for (int j = 0; j < 4; j++)
      glds16(Bp + (size_t)(32 * j) * Sc + k0, dB + j * 2048);
    __syncthreads();

    // s2 partials: re-read own staged chunks (rows r0, r0+32)
    short8 pa = *(const short8*)&smA[t * 8];
    short8 pb = *(const short8*)&smA[t * 8 + 2048];

    #pragma unroll
    for (int ks = 0; ks < 2; ks++) {
      short8 af[4], bfr[2];
      #pragma unroll
      for (int i = 0; i < 4; i++) {
        int ra = i * 16 + l15;
        af[i] = *(const short8*)&smA[ra * BK + (((ks * 4 + q) ^ (ra & 7)) << 3)];
      }
      #pragma unroll
      for (int i = 0; i < 2; i++) {
        int rb = wc + i * 16 + l15;
        bfr[i] = *(const short8*)&smB[rb * BK + (((ks * 4 + q) ^ (rb & 7)) << 3)];
      }
      #pragma unroll
      for (int mi = 0; mi < 4; mi++)
        #pragma unroll
        for (int ni = 0; ni < 2; ni++)
          acc[mi][ni] = __builtin_amdgcn_mfma_f32_16x16x32_bf16(af[mi], bfr[ni], acc[mi][ni], 0, 0, 0);
    }

    #pragma unroll
    for (int j = 0; j < 8; j++) {
      s2a += __expf(bf2f(pa[j]) * inv1a);
      s2b += __expf(bf2f(pb[j]) * inv1b);
    }
    __syncthreads();
  }

  // reduce s2 across the 8 threads sharing each staged row
  s2a += __shfl_xor(s2a, 1); s2a += __shfl_xor(s2a, 2); s2a += __shfl_xor(s2a, 4);
  s2b += __shfl_xor(s2b, 1); s2b += __shfl_xor(s2b, 2); s2b += __shfl_xor(s2b, 4);
  if ((t & 7) == 0) {
    s2[z * Sc + m0 + r0] = s2a;
    s2[z * Sc + m0 + r0 + 32] = s2b;
  }

  // epilogue: scale by inv1, transpose in LDS (smB free), coalesced nt writes
  float iv[4][4];
  #pragma unroll
  for (int mi = 0; mi < 4; mi++)
    #pragma unroll
    for (int rr = 0; rr < 4; rr++)
      iv[mi][rr] = 1.0f / s1[z * Sc + m0 + mi * 16 + q * 4 + rr];

  #pragma unroll
  for (int mi = 0; mi < 4; mi++)
    #pragma unroll
    for (int ni = 0; ni < 2; ni++) {
      const int d = wc + ni * 16 + l15;
      #pragma unroll
      for (int rr = 0; rr < 4; rr++) {
        const int il = mi * 16 + q * 4 + rr;      // 0..63
        smB[d * 64 + il] = f2bf(acc[mi][ni][rr] * iv[mi][rr]);
      }
    }
  __syncthreads();

  u16* C = valT + (size_t)z * Dc * Sc;
  const int dd = t >> 1, i0 = (t & 1) * 32;       // thread covers 32 u16 of row dd
  #pragma unroll
  for (int j = 0; j < 4; j++) {
    short8 v = *(const short8*)&smB[dd * 64 + i0 + j * 8];
    __builtin_nontemporal_store(v, (short8*)&C[(size_t)dd * Sc + m0 + i0 + j * 8]);
  }
}

// ---- K4: a2 = exp(P*inv1)*inv2 -> fp32 attnL (nt, output 1); attn_output = a2 @ values ----
__global__ __launch_bounds__(256) void wv_kernel(
    const u16* __restrict__ P, const u16* __restrict__ valT,
    const float* __restrict__ s1, const float* __restrict__ s2,
    float* __restrict__ a2out, u16* __restrict__ aox) {
  __shared__ __align__(16) u16 smA[64 * BK];
  __shared__ __align__(16) u16 smB[128 * BK];
  floatx4 acc[4][2] = {};
  const int z = blockIdx.z;
  const int m0 = blockIdx.y * 64;
  const int t = threadIdx.x, lane = t & 63, w = t >> 6;
  const int wc = w * 32;
  const int l15 = lane & 15, q = lane >> 4;

  const int r = t >> 2;                // A row 0..63 (4 threads/row)
  const int cg2 = (t & 3) * 2;         // logical chunks {cg2, cg2+1}
  const int r0b = t >> 3;
  const int c0b = (t & 7) ^ (r0b & 7);
  const u16* Bp = valT + (size_t)z * Dc * Sc + (size_t)r0b * Sc + c0b * 8;
  u16* dB = smB + w * 512;

  const u16* Prow = P + (size_t)z * Sc * Sc + (size_t)(m0 + r) * Sc + cg2 * 8;
  float* Orow = a2out + (size_t)z * Sc * Sc + (size_t)(m0 + r) * Sc + cg2 * 8;
  const float inv1 = 1.0f / s1[z * Sc + m0 + r];
  const float inv2 = 1.0f / s2[z * Sc + m0 + r];

  for (int k0 = 0; k0 < Sc; k0 += BK) {
    #pragma unroll
    for (int j = 0; j < 4; j++)
      glds16(Bp + (size_t)(32 * j) * Sc + k0, dB + j * 2048);

    short8 p0 = __builtin_nontemporal_load((const short8*)(Prow + k0));
    short8 p1 = __builtin_nontemporal_load((const short8*)(Prow + k0 + 8));
    float4 f[4];
    float* e = (float*)f;
    #pragma unroll
    for (int j = 0; j < 8; j++) e[j] = __expf(bf2f(p0[j]) * inv1) * inv2;
    #pragma unroll
    for (int j = 0; j < 8; j++) e[8 + j] = __expf(bf2f(p1[j]) * inv1) * inv2;
    #pragma unroll
    for (int j = 0; j < 4; j++)
      __builtin_nontemporal_store(__builtin_bit_cast(f32x4v, f[j]),
                                  (f32x4v*)(Orow + k0) + j);  // attention_weights out
    short8 a0 = pack2(f[0], f[1]);
    short8 a1v = pack2(f[2], f[3]);
    *(short8*)&smA[r * BK + (((cg2 + 0) ^ (r & 7)) << 3)] = a0;
    *(short8*)&smA[r * BK + (((cg2 + 1) ^ (r & 7)) << 3)] = a1v;
    __syncthreads();

    #pragma unroll
    for (int ks = 0; ks < 2; ks++) {
      short8 af[4], bfr[2];
      #pragma unroll
      for (int i = 0; i < 4; i++) {
        int ra = i * 16 + l15;
        af[i] = *(const short8*)&smA[ra * BK + (((ks * 4 + q) ^ (ra & 7)) << 3)];
      }
      #pragma unroll
      for (int i = 0; i < 2; i++) {
        int rb = wc + i * 16 + l15;
        bfr[i] = *(const short8*)&smB[rb * BK + (((ks * 4 + q) ^ (rb & 7)) << 3)];
      }
      #pragma unroll
      for (int mi = 0; mi < 4; mi++)
        #pragma unroll
        for (int ni = 0; ni < 2; ni++)
          acc[mi][ni] = __builtin_amdgcn_mfma_f32_16x16x32_bf16(af[mi], bfr[ni], acc[mi][ni], 0, 0, 0);
    }
    __syncthreads();
  }

  const int b = z >> 4, h = z & 15;
  #pragma unroll
  for (int mi = 0; mi < 4; mi++)
    #pragma unroll
    for (int ni = 0; ni < 2; ni++) {
      const int gcol = wc + ni * 16 + l15;   // d
      #pragma unroll
      for (int rr = 0; rr < 4; rr++) {
        const int grow = m0 + mi * 16 + q * 4 + rr;  // s
        __builtin_nontemporal_store((u16)f2bf(acc[mi][ni][rr]),
            &aox[((size_t)b * Sc + grow) * Ec + h * Dc + gcol]);
      }
    }
}

// ---- K5: out = aox @ Wo + bo -> fp32 d_out region 0 ----
__global__ __launch_bounds__(256) void out_kernel(
    const u16* __restrict__ aox, const u16* __restrict__ WoT,
    const float* __restrict__ bo, float* __restrict__ outp) {
  __shared__ __align__(16) u16 smA[TILE * BK];
  __shared__ __align__(16) u16 smB[TILE * BK];
  floatx4 acc[4][4] = {};
  // XCD-aware swizzle: 512 blocks = 8 * 64
  const int lin = blockIdx.y * 16 + blockIdx.x;
  const int swz = (lin & 7) * 64 + (lin >> 3);
  const int m0 = (swz / 16) * TILE, n0 = (swz % 16) * TILE;
  gemm_core(aox, Ec, WoT, Ec, Ec, m0, n0, smA, smB, acc);

  const int t = threadIdx.x, lane = t & 63, w = t >> 6;
  const int wr = (w >> 1) * 64, wc = (w & 1) * 64, l15 = lane & 15, q = lane >> 4;
  #pragma unroll
  for (int mi = 0; mi < 4; mi++)
    #pragma unroll
    for (int ni = 0; ni < 4; ni++) {
      const int gcol = n0 + wc + ni * 16 + l15;
      const float bias = bo[gcol];
      #pragma unroll
      for (int rr = 0; rr < 4; rr++) {
        const int grow = m0 + wr + mi * 16 + q * 4 + rr;
        __builtin_nontemporal_store(acc[mi][ni][rr] + bias,
                                    &outp[(size_t)grow * Ec + gcol]);
      }
    }
}

extern "C" void kernel_launch(void* const* d_in, const int* in_sizes, int n_in,
                              void* d_out, int out_size, void* d_ws, size_t ws_size,
                              hipStream_t stream) {
  const float* x     = (const float*)d_in[0];
  const float* sinp  = (const float*)d_in[1];
  const float* cosp  = (const float*)d_in[2];
  const int*   maskp = (const int*)d_in[3];
  const float* Wq    = (const float*)d_in[4];
  const float* bq    = (const float*)d_in[5];
  const float* Wk    = (const float*)d_in[6];
  const float* bk    = (const float*)d_in[7];
  const float* Wv    = (const float*)d_in[8];
  const float* bv    = (const float*)d_in[9];
  const float* Wo    = (const float*)d_in[10];
  const float* bo    = (const float*)d_in[11];

  float* out0  = (float*)d_out;                         // (B,S,E) fp32
  float* attnL = out0 + (size_t)Bc * Sc * Ec;           // (B,H,S,S): attention_weights fp32

  // workspace (u16 elems unless noted)
  u16* wsp  = (u16*)d_ws;
  u16* WT   = wsp;                                      // [3E][E]
  u16* WoT  = WT + (size_t)3 * Ec * Ec;                 // [E][E]
  u16* xb   = WoT + (size_t)Ec * Ec;                    // (B,S,E) bf16
  u16* qr   = xb + (size_t)Bc * Sc * Ec;                // (B,H,S,D)
  u16* kr   = qr + (size_t)Bc * Hc * Sc * Dc;
  u16* vT   = kr + (size_t)Bc * Hc * Sc * Dc;           // (B,H,D,S)
  u16* valT = vT + (size_t)Bc * Hc * Sc * Dc;           // (B,H,D,S)
  u16* aox  = valT + (size_t)Bc * Hc * Sc * Dc;         // (B,S,E)
  float* s1 = (float*)(aox + (size_t)Bc * Sc * Ec);     // (B,H,S)
  float* s2 = s1 + (size_t)Bc * Hc * Sc;                // (B,H,S)
  u16* Pbuf = (u16*)(s2 + (size_t)Bc * Hc * Sc);        // (B,H,S,S) bf16 = exp(masked logits)
  u32* mb   = (u32*)(Pbuf + (size_t)Bc * Hc * Sc * Sc); // (B,S,S/32) bit-packed mask

  transpose_w<<<dim3(64, 64, 4), dim3(32, 8), 0, stream>>>(Wq, Wk, Wv, Wo, WT, WoT);
  xcvt_kernel<<<dim3(4096), 256, 0, stream>>>(x, xb, s1, maskp, mb);
  qkv_kernel<<<dim3(48, 32), 256, 0, stream>>>(xb, WT, bq, bk, bv, sinp, cosp, qr, kr, vT);
  logits_kernel<<<dim3(16, 16, 32), 256, 0, stream>>>(qr, kr, mb, Pbuf, s1);
  av_kernel<<<dim3(1, 32, 32), 256, 0, stream>>>(Pbuf, vT, s1, valT, s2);
  wv_kernel<<<dim3(1, 32, 32), 256, 0, stream>>>(Pbuf, valT, s1, s2, attnL, aox);
  out_kernel<<<dim3(16, 32), 256, 0, stream>>>(aox, WoT, bo, out0);
}

// Round 7
// 1294.267 us; speedup vs baseline: 1.3594x; 1.3594x over previous
//
#include <hip/hip_runtime.h>

typedef unsigned short u16;
typedef unsigned int u32;
typedef __attribute__((ext_vector_type(8))) short short8;   // 8 x bf16 raw
typedef __attribute__((ext_vector_type(4))) float floatx4;  // MFMA acc

constexpr int Bc = 2, Sc = 2048, Ec = 2048, Hc = 16, Dc = 128;
constexpr int TILE = 128, BK = 64;

// fp32 -> bf16 raw bits, round-to-nearest-even
__device__ __forceinline__ u16 f2bf(float f) {
  u32 u = __builtin_bit_cast(u32, f);
  u = (u + 0x7FFFu + ((u >> 16) & 1u)) >> 16;
  return (u16)u;
}

__device__ __forceinline__ float bf2f(short s) {
  u32 u = ((u32)(u16)s) << 16;
  return __builtin_bit_cast(float, u);
}

__device__ __forceinline__ short8 pack2(float4 a, float4 b) {
  short8 r;
  r[0] = (short)f2bf(a.x); r[1] = (short)f2bf(a.y);
  r[2] = (short)f2bf(a.z); r[3] = (short)f2bf(a.w);
  r[4] = (short)f2bf(b.x); r[5] = (short)f2bf(b.y);
  r[6] = (short)f2bf(b.z); r[7] = (short)f2bf(b.w);
  return r;
}

// async 16B global -> LDS (DMA). LDS dest is wave-uniform base + lane*16.
__device__ __forceinline__ void glds16(const u16* g, u16* l) {
  __builtin_amdgcn_global_load_lds(
      (const __attribute__((address_space(1))) u32*)g,
      (__attribute__((address_space(3))) u32*)l, 16, 0, 0);
}

// 128x128 tile GEMM core, BK=64 (2 MFMA k-slices per barrier pair).
// C[m][n] = sum_k A[m][k] * Bt[n][k], both bf16 K-major.
// 256 threads = 4 waves 2x2; each wave 4x4 MFMA tiles of 16x16x32 bf16.
// LDS [128][64] bf16 per operand; chunk c of row r at physical slot c^(r&7),
// staged via pre-swizzled global source.
__device__ __forceinline__ void gemm_core(const u16* __restrict__ A, int lda,
                                          const u16* __restrict__ Bt, int ldb,
                                          int K, int m0, int n0,
                                          u16* smA, u16* smB,
                                          floatx4 (*acc)[4]) {
  const int t = threadIdx.x;
  const int lane = t & 63;
  const int w = t >> 6;
  const int wr = (w >> 1) * 64, wc = (w & 1) * 64;
  const int l15 = lane & 15, q = lane >> 4;

  const int r0 = t >> 3;                 // 0..31
  const int c0 = (t & 7) ^ (r0 & 7);     // pre-swizzled logical k-chunk
  const u16* Ap = A + (size_t)(m0 + r0) * lda + c0 * 8;
  const u16* Bp = Bt + (size_t)(n0 + r0) * ldb + c0 * 8;
  u16* dA = smA + w * 512;               // + j*2048 per 32-row group
  u16* dB = smB + w * 512;

  for (int k0 = 0; k0 < K; k0 += BK) {
    #pragma unroll
    for (int j = 0; j < 4; j++) {
      glds16(Ap + (size_t)(32 * j) * lda + k0, dA + j * 2048);
      glds16(Bp + (size_t)(32 * j) * ldb + k0, dB + j * 2048);
    }
    __syncthreads();                     // drains vmcnt before ds_read

    #pragma unroll
    for (int ks = 0; ks < 2; ks++) {
      short8 af[4], bfr[4];
      #pragma unroll
      for (int i = 0; i < 4; i++) {
        int ra = wr + i * 16 + l15;
        af[i] = *(const short8*)&smA[ra * BK + (((ks * 4 + q) ^ (ra & 7)) << 3)];
        int rb = wc + i * 16 + l15;
        bfr[i] = *(const short8*)&smB[rb * BK + (((ks * 4 + q) ^ (rb & 7)) << 3)];
      }
      #pragma unroll
      for (int mi = 0; mi < 4; mi++)
        #pragma unroll
        for (int ni = 0; ni < 4; ni++)
          acc[mi][ni] = __builtin_amdgcn_mfma_f32_16x16x32_bf16(af[mi], bfr[ni], acc[mi][ni], 0, 0, 0);
    }
    __syncthreads();
  }
}

// ---- weight pre-transpose: WT[n][k] (bf16) from W[k][n] (fp32) ----
__global__ __launch_bounds__(256) void transpose_w(
    const float* __restrict__ Wq, const float* __restrict__ Wk,
    const float* __restrict__ Wv, const float* __restrict__ Wo,
    u16* __restrict__ WT, u16* __restrict__ WoT) {
  __shared__ float tile[32][33];
  const int z = blockIdx.z;
  const float* W = (z == 0) ? Wq : (z == 1) ? Wk : (z == 2) ? Wv : Wo;
  u16* dst = (z < 3) ? (WT + (size_t)z * Ec * Ec) : WoT;
  const int n0 = blockIdx.x * 32, k0 = blockIdx.y * 32;
  const int tx = threadIdx.x, ty = threadIdx.y;
  #pragma unroll
  for (int i = 0; i < 4; i++)
    tile[ty + 8 * i][tx] = W[(size_t)(k0 + ty + 8 * i) * Ec + n0 + tx];
  __syncthreads();
  #pragma unroll
  for (int i = 0; i < 4; i++)
    dst[(size_t)(n0 + ty + 8 * i) * Ec + k0 + tx] = f2bf(tile[tx][ty + 8 * i]);
}

// ---- x -> bf16; zero s1; bit-pack mask (absorbed, no extra dispatch) ----
__global__ __launch_bounds__(256) void xcvt_kernel(const float* __restrict__ x,
                                                   u16* __restrict__ xb,
                                                   float* __restrict__ s1,
                                                   const int* __restrict__ mp,
                                                   u32* __restrict__ mb) {
  const int i = blockIdx.x * 256 + threadIdx.x;
  const float4 f0 = ((const float4*)x)[(size_t)i * 2];
  const float4 f1 = ((const float4*)x)[(size_t)i * 2 + 1];
  *(short8*)&xb[(size_t)i * 8] = pack2(f0, f1);
  if (blockIdx.x < 64)
    ((float4*)s1)[i] = make_float4(0.f, 0.f, 0.f, 0.f);  // 64*256*4 = 65536 floats
  if (blockIdx.x < 1024) {                                // 1024*256 = 262144 words
    const int4* src = (const int4*)mp + (size_t)i * 8;
    u32 wv = 0;
    #pragma unroll
    for (int j = 0; j < 8; j++) {
      const int4 v = src[j];
      wv |= (u32)(v.x != 0) << (j * 4 + 0);
      wv |= (u32)(v.y != 0) << (j * 4 + 1);
      wv |= (u32)(v.z != 0) << (j * 4 + 2);
      wv |= (u32)(v.w != 0) << (j * 4 + 3);
    }
    mb[i] = wv;
  }
}

// ---- K1: fused QKV GEMM (N=6144 concat, bf16 A) + bias + RoPE ----
__global__ __launch_bounds__(256) void qkv_kernel(
    const u16* __restrict__ xb, const u16* __restrict__ WT,
    const float* __restrict__ bq, const float* __restrict__ bk, const float* __restrict__ bv,
    const float* __restrict__ sinp, const float* __restrict__ cosp,
    u16* __restrict__ qr, u16* __restrict__ kr, u16* __restrict__ vT) {
  __shared__ __align__(16) u16 smA[TILE * BK];
  __shared__ __align__(16) u16 smB[TILE * BK];
  floatx4 acc[4][4] = {};
  // XCD-aware swizzle: 1536 blocks = 8 * 192
  const int lin = blockIdx.y * 48 + blockIdx.x;
  const int swz = (lin & 7) * 192 + (lin >> 3);
  const int m0 = (swz / 48) * TILE, n0 = (swz % 48) * TILE;
  gemm_core(xb, Ec, WT, Ec, Ec, m0, n0, smA, smB, acc);

  const int t = threadIdx.x, lane = t & 63, w = t >> 6;
  const int wr = (w >> 1) * 64, wc = (w & 1) * 64, l15 = lane & 15, q = lane >> 4;
  #pragma unroll
  for (int mi = 0; mi < 4; mi++) {
    #pragma unroll
    for (int ni = 0; ni < 4; ni++) {
      const int gcol = n0 + wc + ni * 16 + l15;
      const int which = gcol >> 11;          // 0:q 1:k 2:v
      const int e = gcol & 2047, h = e >> 7, d = e & 127;
      const float* bp = (which == 0) ? bq : (which == 1) ? bk : bv;
      const float bias = bp[e];
      #pragma unroll
      for (int rr = 0; rr < 4; rr++) {
        const int grow = m0 + wr + mi * 16 + q * 4 + rr;
        const int b = grow >> 11, s = grow & 2047;
        float val = acc[mi][ni][rr] + bias;
        float pv = __shfl_xor(val, 1);       // partner column (d^1), same row
        if (which < 2) {
          const size_t sc = ((size_t)h * Sc + s) * Dc + d;
          const float c = cosp[sc], sn = sinp[sc];
          const float o = val * c + ((d & 1) ? pv : -pv) * sn;
          u16* dst = which ? kr : qr;
          dst[(((size_t)b * Hc + h) * Sc + s) * Dc + d] = f2bf(o);
        } else {
          vT[(((size_t)b * Hc + h) * Dc + d) * Sc + s] = f2bf(val);
        }
      }
    }
  }
}

// ---- K2: P = exp(mask(q k^T / sqrt(D))) -> bf16 Pbuf; s1 += per-row sum P ----
__global__ __launch_bounds__(256) void logits_kernel(
    const u16* __restrict__ qr, const u16* __restrict__ kr,
    const u32* __restrict__ mb, u16* __restrict__ Pbuf, float* __restrict__ s1) {
  __shared__ __align__(16) u16 smA[TILE * BK];
  __shared__ __align__(16) u16 smB[TILE * BK];
  floatx4 acc[4][4] = {};
  const int z = blockIdx.z;                  // b*H + h
  const int m0 = blockIdx.y * TILE, n0 = blockIdx.x * TILE;
  gemm_core(qr + (size_t)z * Sc * Dc, Dc, kr + (size_t)z * Sc * Dc, Dc, Dc, m0, n0, smA, smB, acc);

  u16* Pp = Pbuf + (size_t)z * Sc * Sc;
  const int b = z >> 4;
  const float scale = 0.08838834764831845f;  // 1/sqrt(128)
  const int t = threadIdx.x, lane = t & 63, w = t >> 6;
  const int wr = (w >> 1) * 64, wc = (w & 1) * 64, l15 = lane & 15, q = lane >> 4;
  const int wbase = (n0 + wc) >> 5;          // (n0+wc) % 32 == 0

  #pragma unroll
  for (int mi = 0; mi < 4; mi++)
    #pragma unroll
    for (int rr = 0; rr < 4; rr++) {
      const int grow = m0 + wr + mi * 16 + q * 4 + rr;
      const u32* mrow = mb + ((size_t)b * Sc + grow) * (Sc / 32) + wbase;
      const u32 w0 = mrow[0], w1 = mrow[1];  // the wave's 64-col span
      float rsv = 0.f;
      #pragma unroll
      for (int ni = 0; ni < 4; ni++) {
        const int gcol = n0 + wc + ni * 16 + l15;
        const u32 mw = (ni < 2) ? w0 : w1;
        const int mv = (mw >> (gcol & 31)) & 1;
        const float val = mv ? acc[mi][ni][rr] * scale : -9.0e15f;
        const float pe = __expf(val);        // exp(-9e15) -> 0
        rsv += pe;
        Pp[(size_t)grow * Sc + gcol] = f2bf(pe);
      }
      rsv += __shfl_xor(rsv, 1);
      rsv += __shfl_xor(rsv, 2);
      rsv += __shfl_xor(rsv, 4);
      rsv += __shfl_xor(rsv, 8);
      if (l15 == 0) atomicAdd(&s1[z * Sc + grow], rsv);
    }
}

// ---- K3: valT = ((P @ v) * inv1)^T ; s2[row] = sum_k exp(P[row][k]*inv1) ----
// M-tile 64, BK=64; epilogue transposes via LDS for coalesced valT writes.
__global__ __launch_bounds__(256) void av_kernel(
    const u16* __restrict__ P, const u16* __restrict__ vT,
    const float* __restrict__ s1, u16* __restrict__ valT, float* __restrict__ s2) {
  __shared__ __align__(16) u16 smA[64 * BK];    // [64][64] 8KB
  __shared__ __align__(16) u16 smB[128 * BK];   // [128][64] 16KB
  floatx4 acc[4][2] = {};
  const int z = blockIdx.z;
  const int m0 = blockIdx.y * 64;
  const int t = threadIdx.x, lane = t & 63, w = t >> 6;
  const int wc = w * 32;
  const int l15 = lane & 15, q = lane >> 4;

  const int r0 = t >> 3;               // 0..31
  const int c0 = (t & 7) ^ (r0 & 7);   // pre-swizzled logical k-chunk
  const u16* Pb = P + (size_t)z * Sc * Sc;
  const u16* Ap = Pb + (size_t)(m0 + r0) * Sc + c0 * 8;   // A rows r0, r0+32
  const u16* Bp = vT + (size_t)z * Dc * Sc + (size_t)r0 * Sc + c0 * 8;
  u16* dA = smA + w * 512;
  u16* dB = smB + w * 512;

  const float inv1a = 1.0f / s1[z * Sc + m0 + r0];
  const float inv1b = 1.0f / s1[z * Sc + m0 + r0 + 32];
  float s2a = 0.0f, s2b = 0.0f;

  for (int k0 = 0; k0 < Sc; k0 += BK) {
    glds16(Ap + k0, dA);
    glds16(Ap + (size_t)32 * Sc + k0, dA + 2048);
    #pragma unroll
    for (int j = 0; j < 4; j++)
      glds16(Bp + (size_t)(32 * j) * Sc + k0, dB + j * 2048);
    __syncthreads();

    // s2 partials: re-read own staged chunks (rows r0, r0+32)
    short8 pa = *(const short8*)&smA[t * 8];
    short8 pb = *(const short8*)&smA[t * 8 + 2048];

    #pragma unroll
    for (int ks = 0; ks < 2; ks++) {
      short8 af[4], bfr[2];
      #pragma unroll
      for (int i = 0; i < 4; i++) {
        int ra = i * 16 + l15;
        af[i] = *(const short8*)&smA[ra * BK + (((ks * 4 + q) ^ (ra & 7)) << 3)];
      }
      #pragma unroll
      for (int i = 0; i < 2; i++) {
        int rb = wc + i * 16 + l15;
        bfr[i] = *(const short8*)&smB[rb * BK + (((ks * 4 + q) ^ (rb & 7)) << 3)];
      }
      #pragma unroll
      for (int mi = 0; mi < 4; mi++)
        #pragma unroll
        for (int ni = 0; ni < 2; ni++)
          acc[mi][ni] = __builtin_amdgcn_mfma_f32_16x16x32_bf16(af[mi], bfr[ni], acc[mi][ni], 0, 0, 0);
    }

    #pragma unroll
    for (int j = 0; j < 8; j++) {
      s2a += __expf(bf2f(pa[j]) * inv1a);
      s2b += __expf(bf2f(pb[j]) * inv1b);
    }
    __syncthreads();
  }

  // reduce s2 across the 8 threads sharing each staged row
  s2a += __shfl_xor(s2a, 1); s2a += __shfl_xor(s2a, 2); s2a += __shfl_xor(s2a, 4);
  s2b += __shfl_xor(s2b, 1); s2b += __shfl_xor(s2b, 2); s2b += __shfl_xor(s2b, 4);
  if ((t & 7) == 0) {
    s2[z * Sc + m0 + r0] = s2a;
    s2[z * Sc + m0 + r0 + 32] = s2b;
  }

  // epilogue: scale by inv1, transpose in LDS (smB free), coalesced writes
  float iv[4][4];
  #pragma unroll
  for (int mi = 0; mi < 4; mi++)
    #pragma unroll
    for (int rr = 0; rr < 4; rr++)
      iv[mi][rr] = 1.0f / s1[z * Sc + m0 + mi * 16 + q * 4 + rr];

  __syncthreads();
  #pragma unroll
  for (int mi = 0; mi < 4; mi++)
    #pragma unroll
    for (int ni = 0; ni < 2; ni++) {
      const int d = wc + ni * 16 + l15;
      #pragma unroll
      for (int rr = 0; rr < 4; rr++) {
        const int il = mi * 16 + q * 4 + rr;      // 0..63
        smB[d * 64 + il] = f2bf(acc[mi][ni][rr] * iv[mi][rr]);
      }
    }
  __syncthreads();

  u16* C = valT + (size_t)z * Dc * Sc;
  const int dd = t >> 1, i0 = (t & 1) * 32;       // thread covers 32 u16 of row dd
  #pragma unroll
  for (int j = 0; j < 4; j++) {
    short8 v = *(const short8*)&smB[dd * 64 + i0 + j * 8];
    *(short8*)&C[(size_t)dd * Sc + m0 + i0 + j * 8] = v;
  }
}

// ---- K4: a2 = exp(P*inv1)*inv2 -> fp32 attnL (output 1); attn_output = a2 @ values ----
__global__ __launch_bounds__(256) void wv_kernel(
    const u16* __restrict__ P, const u16* __restrict__ valT,
    const float* __restrict__ s1, const float* __restrict__ s2,
    float* __restrict__ a2out, u16* __restrict__ aox) {
  __shared__ __align__(16) u16 smA[64 * BK];
  __shared__ __align__(16) u16 smB[128 * BK];
  floatx4 acc[4][2] = {};
  const int z = blockIdx.z;
  const int m0 = blockIdx.y * 64;
  const int t = threadIdx.x, lane = t & 63, w = t >> 6;
  const int wc = w * 32;
  const int l15 = lane & 15, q = lane >> 4;

  const int r = t >> 2;                // A row 0..63 (4 threads/row)
  const int cg2 = (t & 3) * 2;         // logical chunks {cg2, cg2+1}
  const int r0b = t >> 3;
  const int c0b = (t & 7) ^ (r0b & 7);
  const u16* Bp = valT + (size_t)z * Dc * Sc + (size_t)r0b * Sc + c0b * 8;
  u16* dB = smB + w * 512;

  const u16* Prow = P + (size_t)z * Sc * Sc + (size_t)(m0 + r) * Sc + cg2 * 8;
  float* Orow = a2out + (size_t)z * Sc * Sc + (size_t)(m0 + r) * Sc + cg2 * 8;
  const float inv1 = 1.0f / s1[z * Sc + m0 + r];
  const float inv2 = 1.0f / s2[z * Sc + m0 + r];

  for (int k0 = 0; k0 < Sc; k0 += BK) {
    #pragma unroll
    for (int j = 0; j < 4; j++)
      glds16(Bp + (size_t)(32 * j) * Sc + k0, dB + j * 2048);

    short8 p0 = *(const short8*)(Prow + k0);
    short8 p1 = *(const short8*)(Prow + k0 + 8);
    float4 f[4];
    float* e = (float*)f;
    #pragma unroll
    for (int j = 0; j < 8; j++) e[j] = __expf(bf2f(p0[j]) * inv1) * inv2;
    #pragma unroll
    for (int j = 0; j < 8; j++) e[8 + j] = __expf(bf2f(p1[j]) * inv1) * inv2;
    #pragma unroll
    for (int j = 0; j < 4; j++) ((float4*)(Orow + k0))[j] = f[j];  // attention_weights out
    short8 a0 = pack2(f[0], f[1]);
    short8 a1v = pack2(f[2], f[3]);
    *(short8*)&smA[r * BK + (((cg2 + 0) ^ (r & 7)) << 3)] = a0;
    *(short8*)&smA[r * BK + (((cg2 + 1) ^ (r & 7)) << 3)] = a1v;
    __syncthreads();

    #pragma unroll
    for (int ks = 0; ks < 2; ks++) {
      short8 af[4], bfr[2];
      #pragma unroll
      for (int i = 0; i < 4; i++) {
        int ra = i * 16 + l15;
        af[i] = *(const short8*)&smA[ra * BK + (((ks * 4 + q) ^ (ra & 7)) << 3)];
      }
      #pragma unroll
      for (int i = 0; i < 2; i++) {
        int rb = wc + i * 16 + l15;
        bfr[i] = *(const short8*)&smB[rb * BK + (((ks * 4 + q) ^ (rb & 7)) << 3)];
      }
      #pragma unroll
      for (int mi = 0; mi < 4; mi++)
        #pragma unroll
        for (int ni = 0; ni < 2; ni++)
          acc[mi][ni] = __builtin_amdgcn_mfma_f32_16x16x32_bf16(af[mi], bfr[ni], acc[mi][ni], 0, 0, 0);
    }
    __syncthreads();
  }

  const int b = z >> 4, h = z & 15;
  #pragma unroll
  for (int mi = 0; mi < 4; mi++)
    #pragma unroll
    for (int ni = 0; ni < 2; ni++) {
      const int gcol = wc + ni * 16 + l15;   // d
      #pragma unroll
      for (int rr = 0; rr < 4; rr++) {
        const int grow = m0 + mi * 16 + q * 4 + rr;  // s
        aox[((size_t)b * Sc + grow) * Ec + h * Dc + gcol] = f2bf(acc[mi][ni][rr]);
      }
    }
}

// ---- K5: out = aox @ Wo + bo -> fp32 d_out region 0 ----
__global__ __launch_bounds__(256) void out_kernel(
    const u16* __restrict__ aox, const u16* __restrict__ WoT,
    const float* __restrict__ bo, float* __restrict__ outp) {
  __shared__ __align__(16) u16 smA[TILE * BK];
  __shared__ __align__(16) u16 smB[TILE * BK];
  floatx4 acc[4][4] = {};
  // XCD-aware swizzle: 512 blocks = 8 * 64
  const int lin = blockIdx.y * 16 + blockIdx.x;
  const int swz = (lin & 7) * 64 + (lin >> 3);
  const int m0 = (swz / 16) * TILE, n0 = (swz % 16) * TILE;
  gemm_core(aox, Ec, WoT, Ec, Ec, m0, n0, smA, smB, acc);

  const int t = threadIdx.x, lane = t & 63, w = t >> 6;
  const int wr = (w >> 1) * 64, wc = (w & 1) * 64, l15 = lane & 15, q = lane >> 4;
  #pragma unroll
  for (int mi = 0; mi < 4; mi++)
    #pragma unroll
    for (int ni = 0; ni < 4; ni++) {
      const int gcol = n0 + wc + ni * 16 + l15;
      const float bias = bo[gcol];
      #pragma unroll
      for (int rr = 0; rr < 4; rr++) {
        const int grow = m0 + wr + mi * 16 + q * 4 + rr;
        outp[(size_t)grow * Ec + gcol] = acc[mi][ni][rr] + bias;
      }
    }
}

extern "C" void kernel_launch(void* const* d_in, const int* in_sizes, int n_in,
                              void* d_out, int out_size, void* d_ws, size_t ws_size,
                              hipStream_t stream) {
  const float* x     = (const float*)d_in[0];
  const float* sinp  = (const float*)d_in[1];
  const float* cosp  = (const float*)d_in[2];
  const int*   maskp = (const int*)d_in[3];
  const float* Wq    = (const float*)d_in[4];
  const float* bq    = (const float*)d_in[5];
  const float* Wk    = (const float*)d_in[6];
  const float* bk    = (const float*)d_in[7];
  const float* Wv    = (const float*)d_in[8];
  const float* bv    = (const float*)d_in[9];
  const float* Wo    = (const float*)d_in[10];
  const float* bo    = (const float*)d_in[11];

  float* out0  = (float*)d_out;                         // (B,S,E) fp32
  float* attnL = out0 + (size_t)Bc * Sc * Ec;           // (B,H,S,S): attention_weights fp32

  // workspace (u16 elems unless noted)
  u16* wsp  = (u16*)d_ws;
  u16* WT   = wsp;                                      // [3E][E]
  u16* WoT  = WT + (size_t)3 * Ec * Ec;                 // [E][E]
  u16* xb   = WoT + (size_t)Ec * Ec;                    // (B,S,E) bf16
  u16* qr   = xb + (size_t)Bc * Sc * Ec;                // (B,H,S,D)
  u16* kr   = qr + (size_t)Bc * Hc * Sc * Dc;
  u16* vT   = kr + (size_t)Bc * Hc * Sc * Dc;           // (B,H,D,S)
  u16* valT = vT + (size_t)Bc * Hc * Sc * Dc;           // (B,H,D,S)
  u16* aox  = valT + (size_t)Bc * Hc * Sc * Dc;         // (B,S,E)
  float* s1 = (float*)(aox + (size_t)Bc * Sc * Ec);     // (B,H,S)
  float* s2 = s1 + (size_t)Bc * Hc * Sc;                // (B,H,S)
  u16* Pbuf = (u16*)(s2 + (size_t)Bc * Hc * Sc);        // (B,H,S,S) bf16 = exp(masked logits)
  u32* mb   = (u32*)(Pbuf + (size_t)Bc * Hc * Sc * Sc); // (B,S,S/32) bit-packed mask

  transpose_w<<<dim3(64, 64, 4), dim3(32, 8), 0, stream>>>(Wq, Wk, Wv, Wo, WT, WoT);
  xcvt_kernel<<<dim3(4096), 256, 0, stream>>>(x, xb, s1, maskp, mb);
  qkv_kernel<<<dim3(48, 32), 256, 0, stream>>>(xb, WT, bq, bk, bv, sinp, cosp, qr, kr, vT);
  logits_kernel<<<dim3(16, 16, 32), 256, 0, stream>>>(qr, kr, mb, Pbuf, s1);
  av_kernel<<<dim3(1, 32, 32), 256, 0, stream>>>(Pbuf, vT, s1, valT, s2);
  wv_kernel<<<dim3(1, 32, 32), 256, 0, stream>>>(Pbuf, valT, s1, s2, attnL, aox);
  out_kernel<<<dim3(16, 32), 256, 0, stream>>>(aox, WoT, bo, out0);
}